// Round 4
// baseline (206.054 us; speedup 1.0000x reference)
//
#include <hip/hip_runtime.h>

typedef _Float16 half8 __attribute__((ext_vector_type(8)));
typedef float f32x4 __attribute__((ext_vector_type(4)));
typedef float f32x4u __attribute__((ext_vector_type(4), aligned(4)));

#define SPH  32           // timesteps per phase
#define NIT  34           // 32 compute phases + 2 pipeline-drain iterations
#define SPKW 392          // spk row stride f16: 384 + 8 pad (784 B rows)
#define C2W  48           // c2L row stride (floats)
#define TN   1000

// R15: conv reads moved LDS -> global(L1/L2). Model (fits R11-R14): phase ~
// sum(LDS wave-insts x width cost), b128 ~12cyc, b32/b16 ~6cyc, independent
// of banks touched (m134; R14's conflict-halving was time-neutral). Conv xsT
// reads were 4032 of ~6400 cyc/phase. Per-phase x tile is 3.8KB/CU and 16
// lanes/inst share one address -> read x straight from global via L1 with a
// 1-block register prefetch (t contiguous across phases). xsT + staging waves
// deleted; 768 thr again.
//   waves 0-5 (384 thr): conv+LIF1(ph); global x loads [p..p+3],[p+3..p+6]
//                        (4B-aligned dwordx4, never OOB), ONE neuron/thread
//                        (c=ct&15, p=ct>>4; spike K'=p*16+c as R14).
//   waves 6-11(384 thr): FC GEMM(ph-1): 12 B-loads + 12 MFMA + 1 store.
//   wave 6:              LIF2 scan(ph-2) after GEMM + final output.
// One barrier per iteration; producer->consumer 1 barrier apart.
__global__ __launch_bounds__(768, 3) void snn_fwd(
    const float* __restrict__ x,      // (256,1000,30)
    const float* __restrict__ conv_w, // (16,1,7)
    const float* __restrict__ conv_b, // (16)
    const float* __restrict__ fc_w,   // (35,384)
    const float* __restrict__ fc_b,   // (35)
    float* __restrict__ out)          // (256,35)
{
    __shared__ __align__(16) _Float16 spk[2][SPH][SPKW];   // 50176 B
    __shared__ __align__(16) float    c2L[2][SPH][C2W];    // 12288 B

    const int tid  = threadIdx.x;
    const int b    = blockIdx.x;
    const int wid  = tid >> 6;
    const int lane = tid & 63;

    // ---------- conv setup (wid<6): c-fast mapping, K' = p*16 + c = ct ----------
    const int ct = tid;              // 0..383 when wid<6
    const int c  = ct & 15;
    const int p  = ct >> 4;
    float wk[7];
    float cb = 0.f;
    if (wid < 6) {
#pragma unroll
        for (int k = 0; k < 7; ++k) wk[k] = conv_w[c * 7 + k];
        cb = conv_b[c];
    }

    // ---------- FC setup (wid>=6): g=(wid-6): m=g>>1 (M-tile), tb=g&1 ----------
    const int g  = wid - 6;
    const int m  = g >> 1;
    const int tb = g & 1;
    const int nL = lane & 15;        // B col (t_local); C col
    const int q  = lane >> 4;        // quad: k = q*8 + j
    half8 A[12];
    if (wid >= 6) {
        const int o = m * 16 + nL;
#pragma unroll
        for (int kt = 0; kt < 12; ++kt) {
            half8 a;
#pragma unroll
            for (int j = 0; j < 8; ++j) {
                int Kp = kt * 32 + q * 8 + j;    // permuted K index (p*16+c)
                int Kc = Kp & 15;                 // channel
                int Kq = Kp >> 4;                 // position
                a[j] = (o < 35) ? (_Float16)fc_w[o * 384 + Kc * 24 + Kq]
                                : (_Float16)0.f;
            }
            A[kt] = a;
        }
    }
    const float fcb = (wid == 6 && lane < 35) ? fc_b[lane] : 0.f;

    // ---------- state ----------
    float m1 = 0.f, sp = 0.f;        // LIF1 (one neuron)
    float mem2 = 0.f, accO = 0.f;    // LIF2 (wave6 lanes<35)

    const float* xb = x + (size_t)b * (TN * 30);

    // ---------- conv prefetch regs: block t=0..3 ----------
    f32x4 pA[4], pB[4];
    if (wid < 6) {
#pragma unroll
        for (int dt = 0; dt < 4; ++dt) {
            const float* r = xb + dt * 30 + p;
            pA[dt] = (f32x4)(*(const f32x4u*)r);
            pB[dt] = (f32x4)(*(const f32x4u*)(r + 3));
        }
    }
    // no prologue barrier needed: phase 0 touches no LDS produced by others

#pragma unroll 1
    for (int ph = 0; ph < NIT; ++ph) {
        if (wid < 6) {
            // =================== conv+LIF1(ph): 4 timesteps per block ===================
            if (ph < 32) {
                unsigned short* sdst = (unsigned short*)&spk[ph & 1][0][ct];
                const int T0 = ph * SPH;
#pragma unroll
                for (int s0 = 0; s0 < SPH; s0 += 4) {
                    // consume current prefetch
                    f32x4 cA[4], cB[4];
#pragma unroll
                    for (int dt = 0; dt < 4; ++dt) { cA[dt] = pA[dt]; cB[dt] = pB[dt]; }
                    // issue prefetch for next block (crosses phase boundary; tail clamped)
#pragma unroll
                    for (int dt = 0; dt < 4; ++dt) {
                        int t = T0 + s0 + 4 + dt;
                        t = (t < TN) ? t : (TN - 1);
                        const float* r = xb + t * 30 + p;
                        pA[dt] = (f32x4)(*(const f32x4u*)r);
                        pB[dt] = (f32x4)(*(const f32x4u*)(r + 3));
                    }
                    // compute 4 timesteps
#pragma unroll
                    for (int dt = 0; dt < 4; ++dt) {
                        float c1 = cb;
                        c1 = fmaf(wk[0], cA[dt][0], c1);
                        c1 = fmaf(wk[1], cA[dt][1], c1);
                        c1 = fmaf(wk[2], cA[dt][2], c1);
                        c1 = fmaf(wk[3], cA[dt][3], c1);
                        c1 = fmaf(wk[4], cB[dt][1], c1);
                        c1 = fmaf(wk[5], cB[dt][2], c1);
                        c1 = fmaf(wk[6], cB[dt][3], c1);
                        m1 = fmaf(0.9f, m1, c1 - sp);
                        sp = (m1 > 1.0f) ? 1.0f : 0.0f;
                        sdst[(s0 + dt) * SPKW] =
                            (m1 > 1.0f) ? (unsigned short)0x3C00u : (unsigned short)0u;
                    }
                }
            }
        } else {
            // =================== GEMM(ph-1): this wave's (m, tb) ===================
            if (ph >= 1 && ph <= 32) {
                const _Float16* sb = &spk[(ph - 1) & 1][0][0];
                half8 B[12];
#pragma unroll
                for (int kt = 0; kt < 12; ++kt)
                    B[kt] = *(const half8*)(sb + (tb * 16 + nL) * SPKW + kt * 32 + q * 8);
                f32x4 acc = {0.f, 0.f, 0.f, 0.f};
#pragma unroll
                for (int kt = 0; kt < 12; ++kt)
                    acc = __builtin_amdgcn_mfma_f32_16x16x32_f16(A[kt], B[kt], acc, 0, 0, 0);
                // C/D: col = lane&15 (t_local), row = q*4+i (o_local)
                float* cd = &c2L[(ph - 1) & 1][0][0];
                *(f32x4*)(cd + (tb * 16 + nL) * C2W + m * 16 + q * 4) = acc;
            }
            // =================== LIF2 scan(ph-2) (wave 6 lanes<35) ===================
            if (wid == 6 && lane < 35 && ph >= 2) {
                const float* cs = &c2L[(ph - 2) & 1][0][0];
                float v[SPH];
#pragma unroll
                for (int j = 0; j < SPH; ++j) v[j] = cs[j * C2W + lane];
                const int tbase = (ph - 2) * SPH;
#pragma unroll
                for (int j = 0; j < SPH; ++j) {
                    float r2 = (mem2 > 1.0f) ? 1.0f : 0.0f;
                    mem2 = 0.9f * mem2 + (v[j] + fcb) - r2;
                    if (tbase + j < TN) accO += mem2;
                }
            }
        }
        __syncthreads();
    }

    if (wid == 6 && lane < 35) out[b * 35 + lane] = accO * (1.0f / (float)TN);
}

extern "C" void kernel_launch(void* const* d_in, const int* in_sizes, int n_in,
                              void* d_out, int out_size, void* d_ws, size_t ws_size,
                              hipStream_t stream) {
    const float* x      = (const float*)d_in[0];
    const float* conv_w = (const float*)d_in[1];
    const float* conv_b = (const float*)d_in[2];
    const float* fc_w   = (const float*)d_in[3];
    const float* fc_b   = (const float*)d_in[4];
    float* out          = (float*)d_out;

    snn_fwd<<<256, 768, 0, stream>>>(x, conv_w, conv_b, fc_w, fc_b, out);
}

// Round 5
// 150.153 us; speedup vs baseline: 1.3723x; 1.3723x over previous
//
#include <hip/hip_runtime.h>

typedef _Float16 half8 __attribute__((ext_vector_type(8)));
typedef float f32x4 __attribute__((ext_vector_type(4)));

#define SPH  32           // timesteps per phase
#define NIT  34           // 32 compute phases + 2 pipeline-drain iterations
#define SPKW 392          // spk row stride f16: 384 + 8 pad (784 B rows, 16B-aligned)
#define XTW  36           // xsT row stride (floats): 144 B rows, 16B-aligned cols
#define C2W  48           // c2L row stride (floats)
#define TN   1000

// R16: revert R15's global-x (latency-bound, 167us); back to R12/R14 LDS
// structure. Model (fits R11-R14): phase ~ sum(LDS wave-insts x width-cost),
// b128~12cyc, b32/b16~6cyc, banks irrelevant. R14: conv reads 4032 of 6400.
// Change: ONE conv thread = TWO channels (c0=2*(ct&7), c0+1), p=ct>>3 ->
// 3 conv waves instead of 6: xsT read insts halve (336->168). Spikes for
// (c,c+1) are adjacent under K'=p*16+c -> one packed b32 write/step
// (192 b16 -> 96 b32). GEMM/A-permutation/scan unchanged. Staging back on
// GEMM waves, R13-style 2-deep (load ph+2, store ph+1). 576 thr = 9 waves.
//   waves 0-2 (192 thr): conv+LIF1(ph), 2 channels/thread (cpair=ct&7, p=ct>>3)
//   waves 3-8 (384 thr): FC GEMM(ph-1) (12 B-loads + 12 MFMA + 1 store)
//                        + xsT staging (3 floats/thread, 2-phase pipeline)
//   wave 3:              LIF2 scan(ph-2) after GEMM + final output.
// One barrier per iteration; producer->consumer 1 barrier apart.
__global__ __launch_bounds__(576, 1) void snn_fwd(
    const float* __restrict__ x,      // (256,1000,30)
    const float* __restrict__ conv_w, // (16,1,7)
    const float* __restrict__ conv_b, // (16)
    const float* __restrict__ fc_w,   // (35,384)
    const float* __restrict__ fc_b,   // (35)
    float* __restrict__ out)          // (256,35)
{
    __shared__ __align__(16) _Float16 spk[2][SPH][SPKW];   // 50176 B
    __shared__ __align__(16) float    xsT[2][30][XTW];     //  8640 B
    __shared__ __align__(16) float    c2L[2][SPH][C2W];    // 12288 B

    const int tid  = threadIdx.x;
    const int b    = blockIdx.x;
    const int wid  = tid >> 6;
    const int lane = tid & 63;

    // ---------- conv setup (wid<3): thread = (cpair=ct&7, p=ct>>3), 2 channels ----------
    const int ct    = tid;           // 0..191 when wid<3
    const int cpair = ct & 7;
    const int p     = ct >> 3;       // 0..23
    const int c0    = cpair * 2;
    float wk0[7], wk1[7];
    float cb0 = 0.f, cb1 = 0.f;
    if (wid < 3) {
#pragma unroll
        for (int k = 0; k < 7; ++k) {
            wk0[k] = conv_w[c0 * 7 + k];
            wk1[k] = conv_w[(c0 + 1) * 7 + k];
        }
        cb0 = conv_b[c0];
        cb1 = conv_b[c0 + 1];
    }

    // ---------- FC setup (wid 3..8): g=(wid-3): m=g>>1 (M-tile), tb=g&1 ----------
    const int g  = wid - 3;
    const int m  = g >> 1;
    const int tb = g & 1;
    const int nL = lane & 15;        // B col (t_local); C col
    const int q  = lane >> 4;        // quad: k = q*8 + j
    half8 A[12];
    if (wid >= 3) {
        const int o = m * 16 + nL;
#pragma unroll
        for (int kt = 0; kt < 12; ++kt) {
            half8 a;
#pragma unroll
            for (int j = 0; j < 8; ++j) {
                int Kp = kt * 32 + q * 8 + j;    // permuted K index (p*16+c)
                int Kc = Kp & 15;                 // channel
                int Kq = Kp >> 4;                 // position
                a[j] = (o < 35) ? (_Float16)fc_w[o * 384 + Kc * 24 + Kq]
                                : (_Float16)0.f;
            }
            A[kt] = a;
        }
    }
    const float fcb = (wid == 3 && lane < 35) ? fc_b[lane] : 0.f;

    // ---------- staging setup (wid>=3): st = tid-192 in 0..383, 3 floats each ----------
    const int st = tid - 192;
    int fs[3], fl[3];
    if (wid >= 3) {
#pragma unroll
        for (int r = 0; r < 3; ++r) {
            int f = st + 384 * r;    // 0..1151
            fs[r] = f / 30;
            fl[r] = f % 30;
        }
    }

    // ---------- state ----------
    float m1a = 0.f, spa = 0.f;      // LIF1 channel c0
    float m1b = 0.f, spb = 0.f;      // LIF1 channel c0+1
    float mem2 = 0.f, accO = 0.f;    // LIF2 (wave3 lanes<35)
    float xr[3];                     // staging regs, data phase ph+1

    const float* xb = x + (size_t)b * (TN * 30);

    // ---------- prologue (wid>=3): stage xsT[0]; issue loads for data phase 1 ----------
    if (wid >= 3) {
#pragma unroll
        for (int r = 0; r < 3; ++r) {
            int f = st + 384 * r;
            if (f < 960) xsT[0][fl[r]][fs[r]] = xb[f];     // t < 32 < TN
        }
#pragma unroll
        for (int r = 0; r < 3; ++r) {
            int f = st + 384 * r;
            xr[r] = (f < 960) ? xb[960 + f] : 0.f;         // t < 64 < TN
        }
    }
    __syncthreads();

#pragma unroll 1
    for (int ph = 0; ph < NIT; ++ph) {
        if (wid < 3) {
            // =================== conv+LIF1(ph): 2 channels, 4 timesteps/block ===================
            if (ph < 32) {
                const float* xcol = &xsT[ph & 1][p][0];
                unsigned int* sdst =
                    (unsigned int*)&spk[ph & 1][0][p * 16 + c0];
#pragma unroll 2
                for (int s0 = 0; s0 < SPH; s0 += 4) {
                    f32x4 xv[7];
#pragma unroll
                    for (int k = 0; k < 7; ++k)
                        xv[k] = *(const f32x4*)(xcol + k * XTW + s0);
                    float ca[4], cc[4];
#pragma unroll
                    for (int dt = 0; dt < 4; ++dt) { ca[dt] = cb0; cc[dt] = cb1; }
#pragma unroll
                    for (int k = 0; k < 7; ++k) {
#pragma unroll
                        for (int dt = 0; dt < 4; ++dt) {
                            ca[dt] = fmaf(wk0[k], xv[k][dt], ca[dt]);
                            cc[dt] = fmaf(wk1[k], xv[k][dt], cc[dt]);
                        }
                    }
#pragma unroll
                    for (int dt = 0; dt < 4; ++dt) {
                        m1a = fmaf(0.9f, m1a, ca[dt] - spa);
                        spa = (m1a > 1.0f) ? 1.0f : 0.0f;
                        m1b = fmaf(0.9f, m1b, cc[dt] - spb);
                        spb = (m1b > 1.0f) ? 1.0f : 0.0f;
                        unsigned int pk = (m1a > 1.0f ? 0x00003C00u : 0u) |
                                          (m1b > 1.0f ? 0x3C000000u : 0u);
                        // row (s0+dt), half-col p*16+c0 (even) -> 4B-aligned
                        sdst[(s0 + dt) * (SPKW / 2)] = pk;
                    }
                }
            }
        } else {
            // ====== staging loads for data phase ph+2 issued first (latency) ======
            const bool ldg = (ph <= 29);
            float xn[3];
            if (ldg) {
                const float* src = xb + (size_t)(ph + 2) * (SPH * 30);
#pragma unroll
                for (int r = 0; r < 3; ++r) {
                    int f = st + 384 * r;
                    int t = (ph + 2) * SPH + fs[r];
                    xn[r] = (f < 960 && t < TN) ? src[f] : 0.f;
                }
            }
            // =================== GEMM(ph-1): this wave's (m, tb) ===================
            if (ph >= 1 && ph <= 32) {
                const _Float16* sb = &spk[(ph - 1) & 1][0][0];
                half8 B[12];
#pragma unroll
                for (int kt = 0; kt < 12; ++kt)
                    B[kt] = *(const half8*)(sb + (tb * 16 + nL) * SPKW + kt * 32 + q * 8);
                f32x4 acc = {0.f, 0.f, 0.f, 0.f};
#pragma unroll
                for (int kt = 0; kt < 12; ++kt)
                    acc = __builtin_amdgcn_mfma_f32_16x16x32_f16(A[kt], B[kt], acc, 0, 0, 0);
                // C/D: col = lane&15 (t_local), row = q*4+i (o_local)
                float* cd = &c2L[(ph - 1) & 1][0][0];
                *(f32x4*)(cd + (tb * 16 + nL) * C2W + m * 16 + q * 4) = acc;
            }
            // =================== LIF2 scan(ph-2) (wave 3 lanes<35) ===================
            if (wid == 3 && lane < 35 && ph >= 2) {
                const float* cs = &c2L[(ph - 2) & 1][0][0];
                float v[SPH];
#pragma unroll
                for (int j = 0; j < SPH; ++j) v[j] = cs[j * C2W + lane];
                const int tbase = (ph - 2) * SPH;
#pragma unroll
                for (int j = 0; j < SPH; ++j) {
                    float r2 = (mem2 > 1.0f) ? 1.0f : 0.0f;
                    mem2 = 0.9f * mem2 + (v[j] + fcb) - r2;
                    if (tbase + j < TN) accO += mem2;
                }
            }
            // ====== staging store (data ph+1, loaded last phase); then rotate ======
            if (ph <= 30) {
                float* dst = &xsT[(ph + 1) & 1][0][0];
#pragma unroll
                for (int r = 0; r < 3; ++r) {
                    int f = st + 384 * r;
                    if (f < 960) dst[fl[r] * XTW + fs[r]] = xr[r];
                }
            }
            if (ldg) {
#pragma unroll
                for (int r = 0; r < 3; ++r) xr[r] = xn[r];
            }
        }
        __syncthreads();
    }

    if (wid == 3 && lane < 35) out[b * 35 + lane] = accO * (1.0f / (float)TN);
}

extern "C" void kernel_launch(void* const* d_in, const int* in_sizes, int n_in,
                              void* d_out, int out_size, void* d_ws, size_t ws_size,
                              hipStream_t stream) {
    const float* x      = (const float*)d_in[0];
    const float* conv_w = (const float*)d_in[1];
    const float* conv_b = (const float*)d_in[2];
    const float* fc_w   = (const float*)d_in[3];
    const float* fc_b   = (const float*)d_in[4];
    float* out          = (float*)d_out;

    snn_fwd<<<256, 576, 0, stream>>>(x, conv_w, conv_b, fc_w, fc_b, out);
}